// Round 18
// baseline (346.665 us; speedup 1.0000x reference)
//
#include <hip/hip_runtime.h>
#include <stdint.h>

#define BSH 7           // fine bucket shift: 128 cols per bucket
#define BW  128         // fine bucket width
#define SSH 13          // superbucket shift: 8192 cols
#define SBW 8192
#define MAXSB 64        // >= 31 superbuckets
#define CMAX 4096       // LDS edge-cache per binning block
#define RTSH 13         // row-tile shift: 8192 rows (1MB of hs2) per tile
#define NRT 32          // row tiles
#define FPAD 6144       // fine bucket capacity (expected 4094 +/- 64 -> +32 sigma)
#define SPAD 272384     // superbucket capacity (expected 258065 +/- 508 -> +28 sigma)

// ---------------- cursor init (replaces hist+scan: padded buckets need no bases) ----------------
__global__ void k_init(int* __restrict__ cursor, int nbuk, int* __restrict__ scursor, int nsb) {
    int i = blockIdx.x * blockDim.x + threadIdx.x;
    if (i < nbuk) cursor[i] = i * FPAD;
    if (i < nsb)  scursor[i] = i * SPAD;
}

// ---------------- pass 1: bin into superbuckets (padded regions) ----------------
__global__ void k_bin1(const int* __restrict__ ei, int E,
                       int* __restrict__ scursor, unsigned int* __restrict__ tmp) {
    __shared__ int colc[CMAX];
    __shared__ int h[MAXSB], base[MAXSB];
    int start = (int)blockIdx.x * CMAX;
    int end = min(start + CMAX, E);
    int cnt = end - start;
    if (threadIdx.x < MAXSB) h[threadIdx.x] = 0;
    __syncthreads();
    for (int i = threadIdx.x; i < cnt; i += blockDim.x) {
        int c = ei[E + start + i];
        colc[i] = c;
        atomicAdd(&h[c >> SSH], 1);
    }
    __syncthreads();
    if (threadIdx.x < MAXSB) {
        int c = h[threadIdx.x];
        base[threadIdx.x] = c ? atomicAdd(&scursor[threadIdx.x], c) : 0;
        h[threadIdx.x] = 0;                     // reuse as local cursor
    }
    __syncthreads();
    for (int i = threadIdx.x; i < cnt; i += blockDim.x) {
        int r = ei[start + i];
        int c = colc[i];
        int sb = c >> SSH;
        int loc = atomicAdd(&h[sb], 1);
        tmp[base[sb] + loc] = ((unsigned)r << SSH) | (unsigned)(c & (SBW - 1));
    }
}

// ---------------- pass 2: refine superbucket -> 64 fine buckets (padded regions) ----------------
// pairs[pos] = (row << BSH) | (col & (BW-1)). Order within a bucket is
// non-deterministic; all consumers accumulate order-insensitively (f64).
__global__ void k_bin2(const unsigned int* __restrict__ tmp, const int* __restrict__ send,
                       int* __restrict__ cursor, unsigned int* __restrict__ pairs) {
    __shared__ unsigned int cache[CMAX];
    __shared__ int h[64], base[64];
    int sb = blockIdx.x;
    int s = sb * SPAD;
    int cnt = send[sb] - s;
    int chunk = (cnt + (int)gridDim.y - 1) / (int)gridDim.y;
    int start = s + (int)blockIdx.y * chunk;
    int end = min(start + chunk, s + cnt);
    int m = max(0, end - start);
    if (threadIdx.x < 64) h[threadIdx.x] = 0;
    __syncthreads();
    for (int i = threadIdx.x; i < m; i += blockDim.x) {
        unsigned v = tmp[start + i];
        cache[i] = v;
        atomicAdd(&h[(v & (SBW - 1u)) >> BSH], 1);
    }
    __syncthreads();
    if (threadIdx.x < 64) {
        int c = h[threadIdx.x];
        int fine = (sb << 6) + threadIdx.x;
        base[threadIdx.x] = c ? atomicAdd(&cursor[fine], c) : 0;
        h[threadIdx.x] = 0;                     // reuse as local cursor
    }
    __syncthreads();
    for (int i = threadIdx.x; i < m; i += blockDim.x) {
        unsigned v = cache[i];
        unsigned colLow = v & (SBW - 1u);
        int lb = (int)(colLow >> BSH);
        int loc = atomicAdd(&h[lb], 1);
        pairs[base[lb] + loc] = ((v >> SSH) << BSH) | (colLow & (BW - 1u));
    }
}

// ---------------- pass 3: row-tile reorder + degree/dinv/s4 (fused) ----------------
// Partitions pairs[s..e) by row>>RTSH so k_L2's gather stream walks 1MB hs2
// windows in order; also histograms the 128 cols -> dinv + s4 epilogue.
// Order within (bucket,tile) stays non-deterministic; consumers use f64.
__global__ void k_bin3(unsigned int* __restrict__ pairs, const int* __restrict__ bend,
                       const float* __restrict__ x, const float* __restrict__ y1, int n,
                       float* __restrict__ dinv, float4* __restrict__ s4) {
    __shared__ unsigned int cache[FPAD];
    __shared__ int h[NRT], base[NRT];
    __shared__ int cnt[BW];
    int b = blockIdx.x;
    int s = b * FPAD;
    int e = bend[b];
    int m = e - s;
    if (threadIdx.x < NRT) h[threadIdx.x] = 0;
    if (threadIdx.x < BW) cnt[threadIdx.x] = 0;
    __syncthreads();
    for (int i = threadIdx.x; i < m; i += blockDim.x) {
        unsigned v = pairs[s + i];
        cache[i] = v;
        atomicAdd(&h[(v >> BSH) >> RTSH], 1);
        atomicAdd(&cnt[v & (BW - 1u)], 1);
    }
    __syncthreads();
    if (threadIdx.x == 0) {                     // serial NRT-wide exclusive scan
        int run = 0;
        for (int t = 0; t < NRT; ++t) { base[t] = run; run += h[t]; }
    }
    __syncthreads();
    if (threadIdx.x < NRT) h[threadIdx.x] = 0;  // reuse as cursor
    __syncthreads();
    for (int i = threadIdx.x; i < m; i += blockDim.x) {
        unsigned v = cache[i];
        int t = (int)((v >> BSH) >> RTSH);
        int loc = atomicAdd(&h[t], 1);
        pairs[s + base[t] + loc] = v;
    }
    if (threadIdx.x < BW) {
        int col = (b << BSH) + threadIdx.x;
        if (col < n) {
            float d = rsqrtf((float)cnt[threadIdx.x] + 1.0f);
            dinv[col] = d;
            s4[col] = make_float4(d * x[2 * col], d * x[2 * col + 1], d * y1[col], d);
        }
    }
}

// ---------------- fused layer 1: agg3 -> W1+ReLU -> W2*dinv -> hs2 ----------------
__global__ void k_L1(const unsigned int* __restrict__ pairs, const int* __restrict__ bend,
                     const float4* __restrict__ s4, const float* __restrict__ W1,
                     const float* __restrict__ b1, const float* __restrict__ W2,
                     float* __restrict__ hs2, int n) {
    __shared__ double acc[BW * 3];
    int b = blockIdx.x;
    for (int i = threadIdx.x; i < BW * 3; i += blockDim.x) acc[i] = 0.0;
    __syncthreads();
    int s = b * FPAD;
    int e = bend[b];
    int j = s + threadIdx.x * 8;
    int stride = blockDim.x * 8;
    for (; j + 7 < e; j += stride) {
        unsigned pk0 = pairs[j],     pk1 = pairs[j + 1], pk2 = pairs[j + 2], pk3 = pairs[j + 3];
        unsigned pk4 = pairs[j + 4], pk5 = pairs[j + 5], pk6 = pairs[j + 6], pk7 = pairs[j + 7];
        float4 v0 = s4[pk0 >> BSH];             // 8 independent 16B gathers (L2-resident)
        float4 v1 = s4[pk1 >> BSH];
        float4 v2 = s4[pk2 >> BSH];
        float4 v3 = s4[pk3 >> BSH];
        float4 v4 = s4[pk4 >> BSH];
        float4 v5 = s4[pk5 >> BSH];
        float4 v6 = s4[pk6 >> BSH];
        float4 v7 = s4[pk7 >> BSH];
        int c0 = (int)(pk0 & (BW - 1u)) * 3, c1 = (int)(pk1 & (BW - 1u)) * 3;
        int c2 = (int)(pk2 & (BW - 1u)) * 3, c3 = (int)(pk3 & (BW - 1u)) * 3;
        int c4 = (int)(pk4 & (BW - 1u)) * 3, c5 = (int)(pk5 & (BW - 1u)) * 3;
        int c6 = (int)(pk6 & (BW - 1u)) * 3, c7 = (int)(pk7 & (BW - 1u)) * 3;
        atomicAdd(&acc[c0 + 0], (double)v0.x);
        atomicAdd(&acc[c0 + 1], (double)v0.y);
        atomicAdd(&acc[c0 + 2], (double)v0.z);
        atomicAdd(&acc[c1 + 0], (double)v1.x);
        atomicAdd(&acc[c1 + 1], (double)v1.y);
        atomicAdd(&acc[c1 + 2], (double)v1.z);
        atomicAdd(&acc[c2 + 0], (double)v2.x);
        atomicAdd(&acc[c2 + 1], (double)v2.y);
        atomicAdd(&acc[c2 + 2], (double)v2.z);
        atomicAdd(&acc[c3 + 0], (double)v3.x);
        atomicAdd(&acc[c3 + 1], (double)v3.y);
        atomicAdd(&acc[c3 + 2], (double)v3.z);
        atomicAdd(&acc[c4 + 0], (double)v4.x);
        atomicAdd(&acc[c4 + 1], (double)v4.y);
        atomicAdd(&acc[c4 + 2], (double)v4.z);
        atomicAdd(&acc[c5 + 0], (double)v5.x);
        atomicAdd(&acc[c5 + 1], (double)v5.y);
        atomicAdd(&acc[c5 + 2], (double)v5.z);
        atomicAdd(&acc[c6 + 0], (double)v6.x);
        atomicAdd(&acc[c6 + 1], (double)v6.y);
        atomicAdd(&acc[c6 + 2], (double)v6.z);
        atomicAdd(&acc[c7 + 0], (double)v7.x);
        atomicAdd(&acc[c7 + 1], (double)v7.y);
        atomicAdd(&acc[c7 + 2], (double)v7.z);
    }
    if (j < e) {
        int lim = min(j + 8, e);
        for (int t = j; t < lim; ++t) {
            unsigned pk = pairs[t];
            float4 v = s4[pk >> BSH];
            int c = (int)(pk & (BW - 1u)) * 3;
            atomicAdd(&acc[c + 0], (double)v.x);
            atomicAdd(&acc[c + 1], (double)v.y);
            atomicAdd(&acc[c + 2], (double)v.z);
        }
    }
    __syncthreads();
    int f = threadIdx.x & 31;
    int g = threadIdx.x >> 5;                   // 16 groups of 32 (512 threads)
    for (int ci = g; ci < BW; ci += 16) {
        int col = (b << BSH) + ci;
        if (col >= n) continue;                 // group-uniform
        float4 sc = s4[col];
        float a0 = (float)acc[ci * 3 + 0] + sc.x;   // + self loop
        float a1 = (float)acc[ci * 3 + 1] + sc.y;
        float a2 = (float)acc[ci * 3 + 2] + sc.z;
        float d = sc.w;
        float t = a0 * W1[f] + a1 * W1[32 + f] + a2 * W1[64 + f];
        float h1 = fmaxf(d * t + b1[f], 0.0f);
        float o = 0.0f;
#pragma unroll
        for (int k = 0; k < 32; ++k)
            o += __shfl(h1, k, 32) * W2[k * 32 + f];
        hs2[(size_t)col * 32 + f] = d * o;
    }
}

// ---------------- fused layer 2 + layer-3 transform: agg32 -> ReLU -> W3 -> hs3 ----------------
__global__ void k_L2(const unsigned int* __restrict__ pairs, const int* __restrict__ bend,
                     const float* __restrict__ hs2, const float* __restrict__ dinv,
                     const float* __restrict__ b2, const float* __restrict__ W3,
                     float* __restrict__ hs3, int n) {
    __shared__ double acc[BW * 32];             // 32 KB -> 4 blocks/CU
    int b = blockIdx.x;
    for (int i = threadIdx.x; i < BW * 32; i += blockDim.x) acc[i] = 0.0;
    __syncthreads();
    int s = b * FPAD;
    int e = bend[b];
    int f = threadIdx.x & 31;
    int g = threadIdx.x >> 5;                   // 16 groups of 32 (512 threads)
    int j = s + (g << 3);
    for (; j + 7 < e; j += 128) {               // 8-deep MLP per group
        unsigned pk0 = pairs[j],     pk1 = pairs[j + 1], pk2 = pairs[j + 2], pk3 = pairs[j + 3];
        unsigned pk4 = pairs[j + 4], pk5 = pairs[j + 5], pk6 = pairs[j + 6], pk7 = pairs[j + 7];
        float v0 = hs2[(size_t)(pk0 >> BSH) * 32 + f];   // 8 independent 128B gathers
        float v1 = hs2[(size_t)(pk1 >> BSH) * 32 + f];
        float v2 = hs2[(size_t)(pk2 >> BSH) * 32 + f];
        float v3 = hs2[(size_t)(pk3 >> BSH) * 32 + f];
        float v4 = hs2[(size_t)(pk4 >> BSH) * 32 + f];
        float v5 = hs2[(size_t)(pk5 >> BSH) * 32 + f];
        float v6 = hs2[(size_t)(pk6 >> BSH) * 32 + f];
        float v7 = hs2[(size_t)(pk7 >> BSH) * 32 + f];
        atomicAdd(&acc[(pk0 & (BW - 1u)) * 32 + f], (double)v0);
        atomicAdd(&acc[(pk1 & (BW - 1u)) * 32 + f], (double)v1);
        atomicAdd(&acc[(pk2 & (BW - 1u)) * 32 + f], (double)v2);
        atomicAdd(&acc[(pk3 & (BW - 1u)) * 32 + f], (double)v3);
        atomicAdd(&acc[(pk4 & (BW - 1u)) * 32 + f], (double)v4);
        atomicAdd(&acc[(pk5 & (BW - 1u)) * 32 + f], (double)v5);
        atomicAdd(&acc[(pk6 & (BW - 1u)) * 32 + f], (double)v6);
        atomicAdd(&acc[(pk7 & (BW - 1u)) * 32 + f], (double)v7);
    }
    if (j < e) {
        int lim = min(j + 8, e);
        for (int t = j; t < lim; ++t) {
            unsigned pk = pairs[t];
            float v = hs2[(size_t)(pk >> BSH) * 32 + f];
            atomicAdd(&acc[(pk & (BW - 1u)) * 32 + f], (double)v);
        }
    }
    __syncthreads();
    for (int ci = g; ci < BW; ci += 16) {
        int col = (b << BSH) + ci;
        if (col >= n) continue;
        float d = dinv[col];
        float h2 = fmaxf(d * ((float)acc[ci * 32 + f] + hs2[(size_t)col * 32 + f]) + b2[f], 0.0f);
        float w = h2 * W3[f];
        for (int off = 16; off > 0; off >>= 1) w += __shfl_down(w, off, 32);
        if (f == 0) hs3[col] = d * w;
    }
}

// ---------------- layer 3 aggregate: scalar, hs3 is 1MB L2-resident ----------------
__global__ void k_L3(const unsigned int* __restrict__ pairs, const int* __restrict__ bend,
                     const float* __restrict__ hs3, const float* __restrict__ dinv,
                     const float* __restrict__ b3, float* __restrict__ out, int n) {
    __shared__ double acc[BW];
    int b = blockIdx.x;
    if (threadIdx.x < BW) acc[threadIdx.x] = 0.0;
    __syncthreads();
    int s = b * FPAD;
    int e = bend[b];
    int j = s + threadIdx.x * 8;
    int stride = blockDim.x * 8;
    for (; j + 7 < e; j += stride) {
        unsigned pk0 = pairs[j],     pk1 = pairs[j + 1], pk2 = pairs[j + 2], pk3 = pairs[j + 3];
        unsigned pk4 = pairs[j + 4], pk5 = pairs[j + 5], pk6 = pairs[j + 6], pk7 = pairs[j + 7];
        float v0 = hs3[pk0 >> BSH];
        float v1 = hs3[pk1 >> BSH];
        float v2 = hs3[pk2 >> BSH];
        float v3 = hs3[pk3 >> BSH];
        float v4 = hs3[pk4 >> BSH];
        float v5 = hs3[pk5 >> BSH];
        float v6 = hs3[pk6 >> BSH];
        float v7 = hs3[pk7 >> BSH];
        atomicAdd(&acc[pk0 & (BW - 1u)], (double)v0);
        atomicAdd(&acc[pk1 & (BW - 1u)], (double)v1);
        atomicAdd(&acc[pk2 & (BW - 1u)], (double)v2);
        atomicAdd(&acc[pk3 & (BW - 1u)], (double)v3);
        atomicAdd(&acc[pk4 & (BW - 1u)], (double)v4);
        atomicAdd(&acc[pk5 & (BW - 1u)], (double)v5);
        atomicAdd(&acc[pk6 & (BW - 1u)], (double)v6);
        atomicAdd(&acc[pk7 & (BW - 1u)], (double)v7);
    }
    if (j < e) {
        int lim = min(j + 8, e);
        for (int t = j; t < lim; ++t) {
            unsigned pk = pairs[t];
            atomicAdd(&acc[pk & (BW - 1u)], (double)hs3[pk >> BSH]);
        }
    }
    __syncthreads();
    int col = (b << BSH) + threadIdx.x;
    if (threadIdx.x < BW && col < n)
        out[col] = dinv[col] * ((float)acc[threadIdx.x] + hs3[col]) + b3[0];
}

// ---------------- launch ----------------

extern "C" void kernel_launch(void* const* d_in, const int* in_sizes, int n_in,
                              void* d_out, int out_size, void* d_ws, size_t ws_size,
                              hipStream_t stream) {
    const float* x  = (const float*)d_in[0];
    const float* y1 = (const float*)d_in[1];
    const int*   ei = (const int*)d_in[2];
    const float* W1 = (const float*)d_in[3];
    const float* b1 = (const float*)d_in[4];
    const float* W2 = (const float*)d_in[5];
    const float* b2 = (const float*)d_in[6];
    const float* W3 = (const float*)d_in[7];
    const float* b3 = (const float*)d_in[8];
    float* out = (float*)d_out;

    const int n = in_sizes[1];          // 250000
    const int E = in_sizes[2] / 2;      // 8000000
    const int nbuk = (n + BW - 1) >> BSH;   // 1954
    const int nsb = (nbuk + 63) >> 6;       // 31 superbuckets

    char* ws = (char*)d_ws;
    size_t off = 0;
    auto alloc = [&](size_t bytes) { char* p = ws + off; off += (bytes + 255) & ~(size_t)255; return p; };
    unsigned int* pairs = (unsigned int*)alloc((size_t)nbuk * FPAD * sizeof(unsigned int)); // 48MB padded
    float*  hs2   = (float*)alloc((size_t)n * 32 * sizeof(float));               // 32MB
    float4* s4    = (float4*)alloc((size_t)n * sizeof(float4));                  // 4MB
    float*  dinv  = (float*)alloc((size_t)n * sizeof(float));
    float*  hs3   = (float*)alloc((size_t)n * sizeof(float));
    int*    cursor= (int*)alloc((size_t)nbuk * sizeof(int));
    int*    scursor = (int*)alloc((size_t)nsb * sizeof(int));
    (void)ws_size;
    // tmp (pass-1 output, 31*SPAD*4 = 33.8MB) aliases hs2+s4 (36MB contiguous):
    // both are dead until after k_bin2 consumes tmp (k_bin3 writes s4, k_L1 writes hs2).
    unsigned int* tmp = (unsigned int*)hs2;

    // padded-bucket cursor init (replaces hist+scan)
    k_init<<<(nbuk + 255) / 256, 256, 0, stream>>>(cursor, nbuk, scursor, nsb);

    // two-pass radix partition + row-tile reorder (fused with degree/dinv/s4)
    const int nbin1 = (E + CMAX - 1) / CMAX;    // 1954 blocks
    k_bin1<<<nbin1, 256, 0, stream>>>(ei, E, scursor, tmp);
    k_bin2<<<dim3(nsb, 72), 256, 0, stream>>>(tmp, scursor, cursor, pairs);
    k_bin3<<<nbuk, 512, 0, stream>>>(pairs, cursor, x, y1, n, dinv, s4);

    // fused layers
    k_L1<<<nbuk, 512, 0, stream>>>(pairs, cursor, s4, W1, b1, W2, hs2, n);
    k_L2<<<nbuk, 512, 0, stream>>>(pairs, cursor, hs2, dinv, b2, W3, hs3, n);
    k_L3<<<nbuk, 512, 0, stream>>>(pairs, cursor, hs3, dinv, b3, out, n);
}

// Round 19
// 341.479 us; speedup vs baseline: 1.0152x; 1.0152x over previous
//
#include <hip/hip_runtime.h>
#include <stdint.h>

#define BSH 7           // fine bucket shift: 128 cols per bucket
#define BW  128         // fine bucket width
#define SSH 13          // superbucket shift: 8192 cols
#define SBW 8192
#define MAXSB 64        // >= 31 superbuckets
#define CMAX 4096       // LDS edge-cache per binning block
#define RTSH 13         // row-tile shift: 8192 rows (1MB of hs2) per tile
#define NRT 32          // row tiles
#define FPAD 6144       // fine bucket capacity (expected 4094 +/- 64 -> +32 sigma)
#define SPAD 272384     // superbucket capacity (expected 258065 +/- 508 -> +28 sigma)

// ---------------- cursor init (replaces hist+scan: padded buckets need no bases) ----------------
__global__ void k_init(int* __restrict__ cursor, int nbuk, int* __restrict__ scursor, int nsb) {
    int i = blockIdx.x * blockDim.x + threadIdx.x;
    if (i < nbuk) cursor[i] = i * FPAD;
    if (i < nsb)  scursor[i] = i * SPAD;
}

// ---------------- pass 1: bin into superbuckets (padded regions) ----------------
__global__ void k_bin1(const int* __restrict__ ei, int E,
                       int* __restrict__ scursor, unsigned int* __restrict__ tmp) {
    __shared__ int colc[CMAX];
    __shared__ int h[MAXSB], base[MAXSB];
    int start = (int)blockIdx.x * CMAX;
    int end = min(start + CMAX, E);
    int cnt = end - start;
    if (threadIdx.x < MAXSB) h[threadIdx.x] = 0;
    __syncthreads();
    for (int i = threadIdx.x; i < cnt; i += blockDim.x) {
        int c = ei[E + start + i];
        colc[i] = c;
        atomicAdd(&h[c >> SSH], 1);
    }
    __syncthreads();
    if (threadIdx.x < MAXSB) {
        int c = h[threadIdx.x];
        base[threadIdx.x] = c ? atomicAdd(&scursor[threadIdx.x], c) : 0;
        h[threadIdx.x] = 0;                     // reuse as local cursor
    }
    __syncthreads();
    for (int i = threadIdx.x; i < cnt; i += blockDim.x) {
        int r = ei[start + i];
        int c = colc[i];
        int sb = c >> SSH;
        int loc = atomicAdd(&h[sb], 1);
        tmp[base[sb] + loc] = ((unsigned)r << SSH) | (unsigned)(c & (SBW - 1));
    }
}

// ---------------- pass 2: refine superbucket -> 64 fine buckets (padded regions) ----------------
// pairs[pos] = (row << BSH) | (col & (BW-1)). Order within a bucket is
// non-deterministic; all consumers accumulate order-insensitively (f64).
__global__ void k_bin2(const unsigned int* __restrict__ tmp, const int* __restrict__ send,
                       int* __restrict__ cursor, unsigned int* __restrict__ pairs) {
    __shared__ unsigned int cache[CMAX];
    __shared__ int h[64], base[64];
    int sb = blockIdx.x;
    int s = sb * SPAD;
    int cnt = send[sb] - s;
    int chunk = (cnt + (int)gridDim.y - 1) / (int)gridDim.y;
    int start = s + (int)blockIdx.y * chunk;
    int end = min(start + chunk, s + cnt);
    int m = max(0, end - start);
    if (threadIdx.x < 64) h[threadIdx.x] = 0;
    __syncthreads();
    for (int i = threadIdx.x; i < m; i += blockDim.x) {
        unsigned v = tmp[start + i];
        cache[i] = v;
        atomicAdd(&h[(v & (SBW - 1u)) >> BSH], 1);
    }
    __syncthreads();
    if (threadIdx.x < 64) {
        int c = h[threadIdx.x];
        int fine = (sb << 6) + threadIdx.x;
        base[threadIdx.x] = c ? atomicAdd(&cursor[fine], c) : 0;
        h[threadIdx.x] = 0;                     // reuse as local cursor
    }
    __syncthreads();
    for (int i = threadIdx.x; i < m; i += blockDim.x) {
        unsigned v = cache[i];
        unsigned colLow = v & (SBW - 1u);
        int lb = (int)(colLow >> BSH);
        int loc = atomicAdd(&h[lb], 1);
        pairs[base[lb] + loc] = ((v >> SSH) << BSH) | (colLow & (BW - 1u));
    }
}

// ---------------- pass 3: row-tile reorder + degree/dinv/s4 (fused) ----------------
// Partitions pairs[s..e) by row>>RTSH so k_L2's gather stream walks 1MB hs2
// windows in order; also histograms the 128 cols -> dinv + s4 epilogue.
// Order within (bucket,tile) stays non-deterministic; consumers use f64.
__global__ void k_bin3(unsigned int* __restrict__ pairs, const int* __restrict__ bend,
                       const float* __restrict__ x, const float* __restrict__ y1, int n,
                       float* __restrict__ dinv, float4* __restrict__ s4) {
    __shared__ unsigned int cache[FPAD];
    __shared__ int h[NRT], base[NRT];
    __shared__ int cnt[BW];
    int b = blockIdx.x;
    int s = b * FPAD;
    int e = bend[b];
    int m = e - s;
    if (threadIdx.x < NRT) h[threadIdx.x] = 0;
    if (threadIdx.x < BW) cnt[threadIdx.x] = 0;
    __syncthreads();
    for (int i = threadIdx.x; i < m; i += blockDim.x) {
        unsigned v = pairs[s + i];
        cache[i] = v;
        atomicAdd(&h[(v >> BSH) >> RTSH], 1);
        atomicAdd(&cnt[v & (BW - 1u)], 1);
    }
    __syncthreads();
    if (threadIdx.x == 0) {                     // serial NRT-wide exclusive scan
        int run = 0;
        for (int t = 0; t < NRT; ++t) { base[t] = run; run += h[t]; }
    }
    __syncthreads();
    if (threadIdx.x < NRT) h[threadIdx.x] = 0;  // reuse as cursor
    __syncthreads();
    for (int i = threadIdx.x; i < m; i += blockDim.x) {
        unsigned v = cache[i];
        int t = (int)((v >> BSH) >> RTSH);
        int loc = atomicAdd(&h[t], 1);
        pairs[s + base[t] + loc] = v;
    }
    if (threadIdx.x < BW) {
        int col = (b << BSH) + threadIdx.x;
        if (col < n) {
            float d = rsqrtf((float)cnt[threadIdx.x] + 1.0f);
            dinv[col] = d;
            s4[col] = make_float4(d * x[2 * col], d * x[2 * col + 1], d * y1[col], d);
        }
    }
}

// ---------------- fused layer 1: agg3 -> W1+ReLU -> W2*dinv -> hs2 ----------------
__global__ void k_L1(const unsigned int* __restrict__ pairs, const int* __restrict__ bend,
                     const float4* __restrict__ s4, const float* __restrict__ W1,
                     const float* __restrict__ b1, const float* __restrict__ W2,
                     float* __restrict__ hs2, int n) {
    __shared__ double acc[BW * 3];
    int b = blockIdx.x;
    for (int i = threadIdx.x; i < BW * 3; i += blockDim.x) acc[i] = 0.0;
    __syncthreads();
    int s = b * FPAD;
    int e = bend[b];
    int j = s + threadIdx.x * 4;
    int stride = blockDim.x * 4;
    for (; j + 3 < e; j += stride) {
        unsigned pk0 = pairs[j], pk1 = pairs[j + 1], pk2 = pairs[j + 2], pk3 = pairs[j + 3];
        float4 v0 = s4[pk0 >> BSH];             // independent 16B gathers (L2-resident)
        float4 v1 = s4[pk1 >> BSH];
        float4 v2 = s4[pk2 >> BSH];
        float4 v3 = s4[pk3 >> BSH];
        int c0 = (int)(pk0 & (BW - 1u)) * 3, c1 = (int)(pk1 & (BW - 1u)) * 3;
        int c2 = (int)(pk2 & (BW - 1u)) * 3, c3 = (int)(pk3 & (BW - 1u)) * 3;
        atomicAdd(&acc[c0 + 0], (double)v0.x);
        atomicAdd(&acc[c0 + 1], (double)v0.y);
        atomicAdd(&acc[c0 + 2], (double)v0.z);
        atomicAdd(&acc[c1 + 0], (double)v1.x);
        atomicAdd(&acc[c1 + 1], (double)v1.y);
        atomicAdd(&acc[c1 + 2], (double)v1.z);
        atomicAdd(&acc[c2 + 0], (double)v2.x);
        atomicAdd(&acc[c2 + 1], (double)v2.y);
        atomicAdd(&acc[c2 + 2], (double)v2.z);
        atomicAdd(&acc[c3 + 0], (double)v3.x);
        atomicAdd(&acc[c3 + 1], (double)v3.y);
        atomicAdd(&acc[c3 + 2], (double)v3.z);
    }
    if (j < e) {
        int lim = min(j + 4, e);
        for (int t = j; t < lim; ++t) {
            unsigned pk = pairs[t];
            float4 v = s4[pk >> BSH];
            int c = (int)(pk & (BW - 1u)) * 3;
            atomicAdd(&acc[c + 0], (double)v.x);
            atomicAdd(&acc[c + 1], (double)v.y);
            atomicAdd(&acc[c + 2], (double)v.z);
        }
    }
    __syncthreads();
    int f = threadIdx.x & 31;
    int g = threadIdx.x >> 5;                   // 8 groups of 32
    for (int ci = g; ci < BW; ci += 8) {
        int col = (b << BSH) + ci;
        if (col >= n) continue;                 // group-uniform
        float4 sc = s4[col];
        float a0 = (float)acc[ci * 3 + 0] + sc.x;   // + self loop
        float a1 = (float)acc[ci * 3 + 1] + sc.y;
        float a2 = (float)acc[ci * 3 + 2] + sc.z;
        float d = sc.w;
        float t = a0 * W1[f] + a1 * W1[32 + f] + a2 * W1[64 + f];
        float h1 = fmaxf(d * t + b1[f], 0.0f);
        float o = 0.0f;
#pragma unroll
        for (int k = 0; k < 32; ++k)
            o += __shfl(h1, k, 32) * W2[k * 32 + f];
        hs2[(size_t)col * 32 + f] = d * o;
    }
}

// ---------------- fused layer 2 + layer-3 transform: agg32 -> ReLU -> W3 -> hs3 ----------------
__global__ void k_L2(const unsigned int* __restrict__ pairs, const int* __restrict__ bend,
                     const float* __restrict__ hs2, const float* __restrict__ dinv,
                     const float* __restrict__ b2, const float* __restrict__ W3,
                     float* __restrict__ hs3, int n) {
    __shared__ double acc[BW * 32];             // 32 KB -> 4 blocks/CU
    int b = blockIdx.x;
    for (int i = threadIdx.x; i < BW * 32; i += blockDim.x) acc[i] = 0.0;
    __syncthreads();
    int s = b * FPAD;
    int e = bend[b];
    int f = threadIdx.x & 31;
    int g = threadIdx.x >> 5;                   // 16 groups of 32 (512 threads)
    int j = s + (g << 3);
    for (; j + 7 < e; j += 128) {               // 8-deep MLP per group
        unsigned pk0 = pairs[j],     pk1 = pairs[j + 1], pk2 = pairs[j + 2], pk3 = pairs[j + 3];
        unsigned pk4 = pairs[j + 4], pk5 = pairs[j + 5], pk6 = pairs[j + 6], pk7 = pairs[j + 7];
        float v0 = hs2[(size_t)(pk0 >> BSH) * 32 + f];   // 8 independent 128B gathers
        float v1 = hs2[(size_t)(pk1 >> BSH) * 32 + f];
        float v2 = hs2[(size_t)(pk2 >> BSH) * 32 + f];
        float v3 = hs2[(size_t)(pk3 >> BSH) * 32 + f];
        float v4 = hs2[(size_t)(pk4 >> BSH) * 32 + f];
        float v5 = hs2[(size_t)(pk5 >> BSH) * 32 + f];
        float v6 = hs2[(size_t)(pk6 >> BSH) * 32 + f];
        float v7 = hs2[(size_t)(pk7 >> BSH) * 32 + f];
        atomicAdd(&acc[(pk0 & (BW - 1u)) * 32 + f], (double)v0);
        atomicAdd(&acc[(pk1 & (BW - 1u)) * 32 + f], (double)v1);
        atomicAdd(&acc[(pk2 & (BW - 1u)) * 32 + f], (double)v2);
        atomicAdd(&acc[(pk3 & (BW - 1u)) * 32 + f], (double)v3);
        atomicAdd(&acc[(pk4 & (BW - 1u)) * 32 + f], (double)v4);
        atomicAdd(&acc[(pk5 & (BW - 1u)) * 32 + f], (double)v5);
        atomicAdd(&acc[(pk6 & (BW - 1u)) * 32 + f], (double)v6);
        atomicAdd(&acc[(pk7 & (BW - 1u)) * 32 + f], (double)v7);
    }
    if (j < e) {
        int lim = min(j + 8, e);
        for (int t = j; t < lim; ++t) {
            unsigned pk = pairs[t];
            float v = hs2[(size_t)(pk >> BSH) * 32 + f];
            atomicAdd(&acc[(pk & (BW - 1u)) * 32 + f], (double)v);
        }
    }
    __syncthreads();
    for (int ci = g; ci < BW; ci += 16) {
        int col = (b << BSH) + ci;
        if (col >= n) continue;
        float d = dinv[col];
        float h2 = fmaxf(d * ((float)acc[ci * 32 + f] + hs2[(size_t)col * 32 + f]) + b2[f], 0.0f);
        float w = h2 * W3[f];
        for (int off = 16; off > 0; off >>= 1) w += __shfl_down(w, off, 32);
        if (f == 0) hs3[col] = d * w;
    }
}

// ---------------- layer 3 aggregate: scalar, hs3 is 1MB L2-resident ----------------
__global__ void k_L3(const unsigned int* __restrict__ pairs, const int* __restrict__ bend,
                     const float* __restrict__ hs3, const float* __restrict__ dinv,
                     const float* __restrict__ b3, float* __restrict__ out, int n) {
    __shared__ double acc[BW];
    int b = blockIdx.x;
    if (threadIdx.x < BW) acc[threadIdx.x] = 0.0;
    __syncthreads();
    int s = b * FPAD;
    int e = bend[b];
    int j = s + threadIdx.x * 4;
    int stride = blockDim.x * 4;
    for (; j + 3 < e; j += stride) {
        unsigned pk0 = pairs[j], pk1 = pairs[j + 1], pk2 = pairs[j + 2], pk3 = pairs[j + 3];
        float v0 = hs3[pk0 >> BSH];
        float v1 = hs3[pk1 >> BSH];
        float v2 = hs3[pk2 >> BSH];
        float v3 = hs3[pk3 >> BSH];
        atomicAdd(&acc[pk0 & (BW - 1u)], (double)v0);
        atomicAdd(&acc[pk1 & (BW - 1u)], (double)v1);
        atomicAdd(&acc[pk2 & (BW - 1u)], (double)v2);
        atomicAdd(&acc[pk3 & (BW - 1u)], (double)v3);
    }
    if (j < e) {
        int lim = min(j + 4, e);
        for (int t = j; t < lim; ++t) {
            unsigned pk = pairs[t];
            atomicAdd(&acc[pk & (BW - 1u)], (double)hs3[pk >> BSH]);
        }
    }
    __syncthreads();
    int col = (b << BSH) + threadIdx.x;
    if (threadIdx.x < BW && col < n)
        out[col] = dinv[col] * ((float)acc[threadIdx.x] + hs3[col]) + b3[0];
}

// ---------------- launch ----------------

extern "C" void kernel_launch(void* const* d_in, const int* in_sizes, int n_in,
                              void* d_out, int out_size, void* d_ws, size_t ws_size,
                              hipStream_t stream) {
    const float* x  = (const float*)d_in[0];
    const float* y1 = (const float*)d_in[1];
    const int*   ei = (const int*)d_in[2];
    const float* W1 = (const float*)d_in[3];
    const float* b1 = (const float*)d_in[4];
    const float* W2 = (const float*)d_in[5];
    const float* b2 = (const float*)d_in[6];
    const float* W3 = (const float*)d_in[7];
    const float* b3 = (const float*)d_in[8];
    float* out = (float*)d_out;

    const int n = in_sizes[1];          // 250000
    const int E = in_sizes[2] / 2;      // 8000000
    const int nbuk = (n + BW - 1) >> BSH;   // 1954
    const int nsb = (nbuk + 63) >> 6;       // 31 superbuckets

    char* ws = (char*)d_ws;
    size_t off = 0;
    auto alloc = [&](size_t bytes) { char* p = ws + off; off += (bytes + 255) & ~(size_t)255; return p; };
    unsigned int* pairs = (unsigned int*)alloc((size_t)nbuk * FPAD * sizeof(unsigned int)); // 48MB padded
    float*  hs2   = (float*)alloc((size_t)n * 32 * sizeof(float));               // 32MB
    float4* s4    = (float4*)alloc((size_t)n * sizeof(float4));                  // 4MB
    float*  dinv  = (float*)alloc((size_t)n * sizeof(float));
    float*  hs3   = (float*)alloc((size_t)n * sizeof(float));
    int*    cursor= (int*)alloc((size_t)nbuk * sizeof(int));
    int*    scursor = (int*)alloc((size_t)nsb * sizeof(int));
    (void)ws_size;
    // tmp (pass-1 output, 31*SPAD*4 = 33.8MB) aliases hs2+s4 (36MB contiguous):
    // both are dead until after k_bin2 consumes tmp (k_bin3 writes s4, k_L1 writes hs2).
    unsigned int* tmp = (unsigned int*)hs2;

    // padded-bucket cursor init (replaces hist+scan)
    k_init<<<(nbuk + 255) / 256, 256, 0, stream>>>(cursor, nbuk, scursor, nsb);

    // two-pass radix partition + row-tile reorder (fused with degree/dinv/s4)
    const int nbin1 = (E + CMAX - 1) / CMAX;    // 1954 blocks
    k_bin1<<<nbin1, 256, 0, stream>>>(ei, E, scursor, tmp);
    k_bin2<<<dim3(nsb, 72), 256, 0, stream>>>(tmp, scursor, cursor, pairs);
    k_bin3<<<nbuk, 512, 0, stream>>>(pairs, cursor, x, y1, n, dinv, s4);

    // fused layers
    k_L1<<<nbuk, 256, 0, stream>>>(pairs, cursor, s4, W1, b1, W2, hs2, n);
    k_L2<<<nbuk, 512, 0, stream>>>(pairs, cursor, hs2, dinv, b2, W3, hs3, n);
    k_L3<<<nbuk, 256, 0, stream>>>(pairs, cursor, hs3, dinv, b3, out, n);
}